// Round 9
// baseline (575.945 us; speedup 1.0000x reference)
//
#include <hip/hip_runtime.h>
#include <hip/hip_bf16.h>
#include <stdint.h>

#define B_     2048
#define WIN_   11
#define K_     4096
#define VOCAB_ 30522
#define NOUT_  18
#define TOPK_  64
#define NPAIR_ (B_ * WIN_)         /* 22528 */
#define PI_F   3.14159274101257324f

#define NCH_    15                 /* chunks per k-slice */
#define CHUNK_  2048               /* entries = 16 KB = 1024 float4 units */
#define UNITS_  1024               /* float4 units per full chunk */
#define UPK_    15261              /* float4 units per k-slice */
#define TAILU_  925                /* units in last chunk */
#define KPB_    16                 /* k per persistent block */
#define NBLK_   (K_ / KPB_)        /* 256 blocks = 1 per CU */
#define GTOT_   (NCH_ * KPB_)      /* 240 chunks per block */
#define PFTH_   1024
#define PRT_    256                /* producer threads = waves 0..3 */
#define CNT_    768                /* consumer threads = waves 4..15 */
#define NPW_    4                  /* producer waves */
#define NCW_    12                 /* consumer waves */
#define PCON_BYTES_ (NPAIR_ * 4)                    /* 90112 */
#define SMEM_BYTES_ (PCON_BYTES_ + 4 * CHUNK_ * 8)  /* 155648 (proven) */

// ---------------------------------------------------------------------------
// Kernel A: per-batch window prep -> cos/sin per (b,w)
// ---------------------------------------------------------------------------
__global__ void prep_kernel(const int* __restrict__ ids, float2* __restrict__ ocs) {
    int b = blockIdx.x * blockDim.x + threadIdx.x;
    if (b >= B_) return;
    const int* row = ids + b * WIN_;
    int poss[WIN_];
    int cnt = 0;
#pragma unroll
    for (int w = 0; w < WIN_; ++w) { cnt += (row[w] != 0); poss[w] = cnt; }
    float fsl = (float)((cnt > 0) ? cnt : WIN_);
#pragma unroll
    for (int w = 0; w < WIN_; ++w) {
        float pos = __fdiv_rn(__fmul_rn(PI_F, (float)poss[w]), fsl);
        float2 o;
        o.x = cosf(pos);
        o.y = sinf(pos);
        ocs[b * WIN_ + w] = o;
    }
}

// ---------------------------------------------------------------------------
// Kernel A2: stable deterministic bucket-by-chunk of the 22528 (b,w) pairs.
// ---------------------------------------------------------------------------
__global__ __launch_bounds__(512) void bucket_kernel(const int* __restrict__ ids,
                                                     const float2* __restrict__ ocs,
                                                     float4* __restrict__ smeta,
                                                     int* __restrict__ chunkstart) {
    __shared__ int lcnt[512 * NCH_];
    __shared__ int segtot[NCH_][8];
    __shared__ int tot[NCH_];
    __shared__ int bbase[NCH_ + 1];
    const int t = threadIdx.x;

#pragma unroll
    for (int c = 0; c < NCH_; ++c) lcnt[t * NCH_ + c] = 0;
    __syncthreads();

    for (int p = t; p < NPAIR_; p += 512) {
        int id = ids[p];
        if (id != 0) lcnt[t * NCH_ + (id / CHUNK_)] += 1;
    }
    __syncthreads();

    if (t < NCH_ * 8) {
        int bkt = t >> 3, seg = t & 7;
        int run = 0;
        for (int i = 0; i < 64; ++i) {
            int idx = (seg * 64 + i) * NCH_ + bkt;
            int tmp = lcnt[idx];
            lcnt[idx] = run;
            run += tmp;
        }
        segtot[bkt][seg] = run;
    }
    __syncthreads();
    if (t < NCH_) {
        int run = 0;
#pragma unroll
        for (int s = 0; s < 8; ++s) { int tmp = segtot[t][s]; segtot[t][s] = run; run += tmp; }
        tot[t] = run;
    }
    __syncthreads();
    if (t == 0) {
        int run = 0;
#pragma unroll
        for (int c = 0; c < NCH_; ++c) { bbase[c] = run; run += tot[c]; }
        bbase[NCH_] = run;
#pragma unroll
        for (int c = 0; c <= NCH_; ++c) chunkstart[c] = bbase[c];
    }
    __syncthreads();
    if (t < NCH_ * 8) {
        int bkt = t >> 3, seg = t & 7;
        int add = segtot[bkt][seg];
        for (int i = 0; i < 64; ++i) lcnt[(seg * 64 + i) * NCH_ + bkt] += add;
    }
    __syncthreads();

    for (int p = t; p < NPAIR_; p += 512) {
        int id = ids[p];
        if (id == 0) continue;
        int bkt = id / CHUNK_;
        int pos = bbase[bkt] + lcnt[t * NCH_ + bkt];
        lcnt[t * NCH_ + bkt] += 1;
        float2 o = ocs[p];
        float4 m;
        m.x = __int_as_float(id);
        m.y = __int_as_float(p);
        m.z = o.x;
        m.w = o.y;
        smeta[pos] = m;
    }
}

// ---------------------------------------------------------------------------
// pair body: bit-identical arithmetic to the passing rounds
// ---------------------------------------------------------------------------
__device__ __forceinline__ void pair_body(const float4 m, const float2* __restrict__ sb,
                                          int lo, float* __restrict__ pcontrib) {
    int id  = __float_as_int(m.x);
    int dst = __float_as_int(m.y);
    float2 g = sb[id - lo];
    float wabs = sqrtf(__fadd_rn(__fmul_rn(g.x, g.x), __fmul_rn(g.y, g.y)));
    float pre = __fadd_rn(__fmul_rn(g.x, m.z), __fmul_rn(g.y, m.w));
    float pim = __fsub_rn(__fmul_rn(g.y, m.z), __fmul_rn(g.x, m.w));
    if (pre < 1e-10f && pre > -1e-10f) pre = 1e-10f;
    if (pim < 1e-10f && pim > -1e-10f) pim = 1e-10f;
    float ang = fabsf(atan2f(pim, pre));
    pcontrib[dst] = __fadd_rn(wabs, ang);
}

// ---------------------------------------------------------------------------
// Kernel B: persistent, 1 block/CU, FULLY ASYNC producer/consumer.
// Waves 0-3 stream W chunks self-timed (named-reg 4-deep pipeline, gated only
// by per-buffer done counters). Waves 4-15 consume when ready posts. No block
// barriers in the main loop; monotonic LDS counters; single-writer pcontrib.
// ---------------------------------------------------------------------------
__global__ __launch_bounds__(PFTH_, 1) void pf_kernel(const float4* __restrict__ W4,
                                                      const float4* __restrict__ smeta,
                                                      const int* __restrict__ chunkstart,
                                                      float* __restrict__ pfT) {
    extern __shared__ char smem[];
    float* pcontrib = (float*)smem;                        // [NPAIR_]
    char*  sbuf     = smem + PCON_BYTES_;                  // [4][16 KB]
    __shared__ int cstart[NCH_ + 1];
    __shared__ int ready_[4];    // buffer b holds chunk g  <=> ready_[b] == g+1 (monotonic)
    __shared__ int prodcnt_[4];  // producer-wave completions per buffer (monotonic)
    __shared__ int done_[4];     // consumer-wave releases per buffer (monotonic)
    __shared__ int kcnt_;        // consumer boundary barrier 1 (monotonic)
    __shared__ int sumcnt_;      // consumer boundary barrier 2 (monotonic)

    const int t = threadIdx.x;
    const int kbase = blockIdx.x * KPB_;

    if (t <= NCH_) cstart[t] = chunkstart[t];
    if (t < 4) { ready_[t] = 0; prodcnt_[t] = 0; done_[t] = 0; }
    if (t == 4) { kcnt_ = 0; }
    if (t == 5) { sumcnt_ = 0; }
    for (int i = t; i < NPAIR_; i += PFTH_) pcontrib[i] = 0.0f;
    __syncthreads();                      // the ONLY block barrier

#define LOADCH(GP, R0, R1, R2, R3)                                               \
    {   int g2_ = (GP);                                                          \
        if (g2_ < GTOT_) {                                                       \
            int kk2_ = g2_ / NCH_, cc2_ = g2_ % NCH_;                            \
            int nu2_ = (cc2_ == NCH_ - 1) ? TAILU_ : UNITS_;                     \
            const float4* src2_ = W4 + (size_t)(kbase + kk2_) * UPK_ + (size_t)cc2_ * UNITS_; \
            if (t < nu2_)            R0 = src2_[t];                              \
            if (PRT_ + t < nu2_)     R1 = src2_[PRT_ + t];                       \
            if (2 * PRT_ + t < nu2_) R2 = src2_[2 * PRT_ + t];                   \
            if (3 * PRT_ + t < nu2_) R3 = src2_[3 * PRT_ + t];                   \
        }                                                                        \
    }

#define PSTEP(GP, R0, R1, R2, R3)                                                \
    {   const int g_ = (GP);                                                     \
        const int b_ = g_ & 3, u_ = g_ >> 2;                                     \
        const int cc_ = g_ % NCH_;                                               \
        const int nu_ = (cc_ == NCH_ - 1) ? TAILU_ : UNITS_;                     \
        while (*(volatile int*)&done_[b_] < u_ * NCW_) __builtin_amdgcn_s_sleep(1); \
        asm volatile("" ::: "memory");                                           \
        float4* dst_ = (float4*)(sbuf + (size_t)b_ * (CHUNK_ * 8));              \
        if (t < nu_)            dst_[t] = R0;                                    \
        if (PRT_ + t < nu_)     dst_[PRT_ + t] = R1;                             \
        if (2 * PRT_ + t < nu_) dst_[2 * PRT_ + t] = R2;                         \
        if (3 * PRT_ + t < nu_) dst_[3 * PRT_ + t] = R3;                         \
        asm volatile("s_waitcnt lgkmcnt(0)" ::: "memory");                       \
        if ((t & 63) == 0) {                                                     \
            int old_ = atomicAdd(&prodcnt_[b_], 1);                              \
            if (old_ == u_ * NPW_ + (NPW_ - 1)) {                                \
                asm volatile("s_waitcnt lgkmcnt(0)" ::: "memory");               \
                *(volatile int*)&ready_[b_] = g_ + 1;                            \
            }                                                                    \
        }                                                                        \
        LOADCH(g_ + 4, R0, R1, R2, R3)                                           \
    }

    if (t < PRT_) {
        // ---------------- producer ----------------
        float4 a0, a1, a2, a3, b0, b1, b2, b3, c0, c1, c2, c3, d0, d1, d2, d3;
        LOADCH(0, a0, a1, a2, a3)
        LOADCH(1, b0, b1, b2, b3)
        LOADCH(2, c0, c1, c2, c3)
        LOADCH(3, d0, d1, d2, d3)
#pragma unroll 1
        for (int g = 0; g < GTOT_; g += 4) {
            PSTEP(g + 0, a0, a1, a2, a3)
            PSTEP(g + 1, b0, b1, b2, b3)
            PSTEP(g + 2, c0, c1, c2, c3)
            PSTEP(g + 3, d0, d1, d2, d3)
        }
    } else {
        // ---------------- consumer ----------------
        const int ct = t - PRT_;
        int cc = 0, kk = 0;
#pragma unroll 1
        for (int g = 0; g < GTOT_; ++g) {
            const int b = g & 3;
            while (*(volatile int*)&ready_[b] < g + 1) __builtin_amdgcn_s_sleep(1);
            asm volatile("" ::: "memory");
            const float2* sb = (const float2*)(sbuf + (size_t)b * (CHUNK_ * 8));
            const int lo = cc * CHUNK_;
            const int cs = cstart[cc], ce = cstart[cc + 1];
            for (int p = cs + ct; p < ce; p += CNT_)
                pair_body(smeta[p], sb, lo, pcontrib);
            asm volatile("s_waitcnt lgkmcnt(0)" ::: "memory");
            if ((t & 63) == 0) atomicAdd(&done_[b], 1);
            if (cc == NCH_ - 1) {
                // ---- k boundary: consumer-only barrier, sum pcontrib in w order
                if ((t & 63) == 0) atomicAdd(&kcnt_, 1);
                while (*(volatile int*)&kcnt_ < (kk + 1) * NCW_) __builtin_amdgcn_s_sleep(1);
                asm volatile("" ::: "memory");
                float* outp = pfT + (size_t)(kbase + kk) * B_;
                for (int bb = ct; bb < B_; bb += CNT_) {
                    float acc = 0.0f;
#pragma unroll
                    for (int w = 0; w < WIN_; ++w)
                        acc = __fadd_rn(acc, pcontrib[bb * WIN_ + w]);
                    outp[bb] = acc;
                }
                asm volatile("s_waitcnt lgkmcnt(0)" ::: "memory");
                if ((t & 63) == 0) atomicAdd(&sumcnt_, 1);
                while (*(volatile int*)&sumcnt_ < (kk + 1) * NCW_) __builtin_amdgcn_s_sleep(1);
                asm volatile("" ::: "memory");
                cc = 0; ++kk;
            } else {
                ++cc;
            }
        }
    }
#undef PSTEP
#undef LOADCH
}

// ---------------------------------------------------------------------------
// Kernel T: transpose [K,B] -> [B,K] via 64x64 LDS tiles
// ---------------------------------------------------------------------------
__global__ __launch_bounds__(256) void transpose_kb(const float* __restrict__ pfT,
                                                    float* __restrict__ pf) {
    __shared__ float tile[64][65];
    int kb = blockIdx.x * 64;
    int bb = blockIdx.y * 64;
    int tx = threadIdx.x & 63;
    int ty = threadIdx.x >> 6;
#pragma unroll
    for (int i = 0; i < 64; i += 4)
        tile[ty + i][tx] = pfT[(size_t)(kb + ty + i) * B_ + (bb + tx)];
    __syncthreads();
#pragma unroll
    for (int i = 0; i < 64; i += 4)
        pf[(size_t)(bb + ty + i) * K_ + (kb + tx)] = tile[tx][ty + i];
}

// ---------------------------------------------------------------------------
// Kernel C: per-row exact top-64 (radix select, jax tie semantics) + logits.
// ---------------------------------------------------------------------------
__global__ __launch_bounds__(256) void topk_logits_kernel(const float* __restrict__ pf,
                                                          const float* __restrict__ w_out,
                                                          const float* __restrict__ b_out,
                                                          float* __restrict__ out) {
    const int b = blockIdx.x;
    const int t = threadIdx.x;
    __shared__ uint32_t srow[K_];
    __shared__ int hist[256];
    __shared__ int sfx[256];
    __shared__ uint32_t sh_prefix;
    __shared__ int sh_need;
    __shared__ int wave_gt[4], wave_eq[4];
    __shared__ int gt_running, eq_running;
    __shared__ int idxlist[TOPK_];
    __shared__ float partial[4][NOUT_];

    const float* rowp = pf + (size_t)b * K_;
    for (int i = t; i < K_; i += 256) srow[i] = __float_as_uint(rowp[i]);
    if (t == 0) { sh_prefix = 0u; sh_need = TOPK_; gt_running = 0; eq_running = 0; }
    __syncthreads();

    for (int pass = 0; pass < 4; ++pass) {
        int shift = 24 - 8 * pass;
        uint32_t himask = (pass == 0) ? 0u : (0xFFFFFFFFu << (shift + 8));
        hist[t] = 0;
        __syncthreads();
        uint32_t prefix = sh_prefix & himask;
        for (int i = t; i < K_; i += 256) {
            uint32_t u = srow[i];
            if ((u & himask) == prefix) atomicAdd(&hist[(u >> shift) & 255], 1);
        }
        __syncthreads();
        sfx[t] = hist[t];
        __syncthreads();
#pragma unroll
        for (int off = 1; off < 256; off <<= 1) {
            int v = (t + off < 256) ? sfx[t + off] : 0;
            __syncthreads();
            sfx[t] += v;
            __syncthreads();
        }
        int need = sh_need;
        int above = (t == 255) ? 0 : sfx[t + 1];
        if (sfx[t] >= need && above < need) {
            sh_prefix |= ((uint32_t)t << shift);
            sh_need = need - above;
        }
        __syncthreads();
    }
    const uint32_t T = sh_prefix;
    const int r = sh_need;
    const int c_gt = TOPK_ - r;

    for (int cbase = 0; cbase < K_; cbase += 256) {
        uint32_t u = srow[cbase + t];
        bool gt = (u > T);
        bool eq = (u == T);
        unsigned long long mg = __ballot(gt);
        unsigned long long me = __ballot(eq);
        int lane = t & 63, wv = t >> 6;
        if (lane == 0) { wave_gt[wv] = __popcll(mg); wave_eq[wv] = __popcll(me); }
        __syncthreads();
        int offg = gt_running, offe = eq_running;
        for (int w2 = 0; w2 < wv; ++w2) { offg += wave_gt[w2]; offe += wave_eq[w2]; }
        unsigned long long lmask = (lane == 0) ? 0ull : ((~0ull) >> (64 - lane));
        int rkg = offg + __popcll(mg & lmask);
        int rke = offe + __popcll(me & lmask);
        if (gt) idxlist[rkg] = cbase + t;
        else if (eq && rke < r) idxlist[c_gt + rke] = cbase + t;
        __syncthreads();
        if (t == 0) {
            gt_running += wave_gt[0] + wave_gt[1] + wave_gt[2] + wave_gt[3];
            eq_running += wave_eq[0] + wave_eq[1] + wave_eq[2] + wave_eq[3];
        }
        __syncthreads();
    }

    {
        int lane = t & 63, wv4 = t >> 6;
        if (lane < NOUT_) {
            const float* wrow = w_out + (size_t)lane * K_;
            float s = 0.0f;
#pragma unroll
            for (int j = 0; j < TOPK_ / 4; ++j) s += wrow[idxlist[wv4 * (TOPK_ / 4) + j]];
            partial[wv4][lane] = s;
        }
        __syncthreads();
        if (t < NOUT_) {
            float s = b_out[t] + partial[0][t] + partial[1][t] + partial[2][t] + partial[3][t];
            out[b * NOUT_ + t] = s;
        }
    }
}

// ---------------------------------------------------------------------------
extern "C" void kernel_launch(void* const* d_in, const int* in_sizes, int n_in,
                              void* d_out, int out_size, void* d_ws, size_t ws_size,
                              hipStream_t stream) {
    const int*   ids   = (const int*)d_in[0];
    const float* W     = (const float*)d_in[1];
    const float* w_out = (const float*)d_in[2];
    const float* b_out = (const float*)d_in[3];
    float* out = (float*)d_out;

    char* ws = (char*)d_ws;
    const size_t pf_bytes = (size_t)K_ * B_ * sizeof(float);   // 33.55 MB
    float*  pfT   = (float*)(ws);                              // [K, B]
    float*  pf    = (float*)(ws + pf_bytes);                   // [B, K]
    float2* ocs   = (float2*)(ws + 2 * pf_bytes);              // [NPAIR_]
    float4* smeta = (float4*)(ws + 2 * pf_bytes + 256 * 1024); // [NPAIR_]
    int* chunkstart = (int*)(ws + 2 * pf_bytes + 768 * 1024);  // [NCH_+1]

    (void)hipFuncSetAttribute((const void*)pf_kernel,
                              hipFuncAttributeMaxDynamicSharedMemorySize,
                              SMEM_BYTES_);

    prep_kernel<<<(B_ + 255) / 256, 256, 0, stream>>>(ids, ocs);
    bucket_kernel<<<1, 512, 0, stream>>>(ids, ocs, smeta, chunkstart);
    pf_kernel<<<NBLK_, PFTH_, SMEM_BYTES_, stream>>>((const float4*)W, smeta, chunkstart, pfT);
    transpose_kb<<<dim3(K_ / 64, B_ / 64), 256, 0, stream>>>(pfT, pf);
    topk_logits_kernel<<<B_, 256, 0, stream>>>(pf, w_out, b_out, out);
}

// Round 10
// 404.537 us; speedup vs baseline: 1.4237x; 1.4237x over previous
//
#include <hip/hip_runtime.h>
#include <hip/hip_bf16.h>
#include <stdint.h>

#define B_     2048
#define WIN_   11
#define K_     4096
#define VOCAB_ 30522
#define NOUT_  18
#define TOPK_  64
#define NPAIR_ (B_ * WIN_)         /* 22528 */
#define PI_F   3.14159274101257324f

#define NCH_    15                 /* chunks per k-slice */
#define CHUNK_  2048               /* entries = 16 KB = 1024 float4 units */
#define UNITS_  1024               /* float4 units per full chunk */
#define UPK_    15261              /* float4 units per k-slice */
#define TAILU_  925                /* units in last chunk */
#define KPB_    16                 /* k per persistent block */
#define NBLK_   (K_ / KPB_)        /* 256 blocks = 1 per CU */
#define GTOT_   (NCH_ * KPB_)      /* 240 phases; % 4 == 0 */
#define PFTH_   1024
#define PRT_    256                /* producer threads = waves 0..3 */
#define CNT_    768                /* consumer threads = waves 4..15 */
#define PCON_BYTES_ (NPAIR_ * 4)                    /* 90112 */
#define SMEM_BYTES_ (PCON_BYTES_ + 4 * CHUNK_ * 8)  /* 155648 (proven) */

static_assert(GTOT_ % 4 == 0, "unroll-4 rotation");

typedef float vf4 __attribute__((ext_vector_type(4)));

// ---------------------------------------------------------------------------
// Kernel A: per-batch window prep -> trig-table index per (b,w)
// tab = (poss-1)*11 + (sl-1); table value computed in pf with the identical
// float formula -> bit-identical cos/sin to all previous passing rounds.
// ---------------------------------------------------------------------------
__global__ void prep_kernel(const int* __restrict__ ids, int* __restrict__ tabv) {
    int b = blockIdx.x * blockDim.x + threadIdx.x;
    if (b >= B_) return;
    const int* row = ids + b * WIN_;
    int poss[WIN_];
    int cnt = 0;
#pragma unroll
    for (int w = 0; w < WIN_; ++w) { cnt += (row[w] != 0); poss[w] = cnt; }
    int sl = (cnt > 0) ? cnt : WIN_;
#pragma unroll
    for (int w = 0; w < WIN_; ++w) {
        int tb = (poss[w] - 1) * 11 + (sl - 1);   // valid (0..120) whenever id!=0
        if (tb < 0) tb = 0;                        // unused slots, keep in range
        tabv[b * WIN_ + w] = tb;
    }
}

// ---------------------------------------------------------------------------
// Kernel A2: stable deterministic bucket-by-chunk of the 22528 (b,w) pairs.
// smeta[pos] = int2{ id, dst | (tab<<16) }; chunkstart[0..NCH_].
// ---------------------------------------------------------------------------
__global__ __launch_bounds__(512) void bucket_kernel(const int* __restrict__ ids,
                                                     const int* __restrict__ tabv,
                                                     int2* __restrict__ smeta,
                                                     int* __restrict__ chunkstart) {
    __shared__ int lcnt[512 * NCH_];
    __shared__ int segtot[NCH_][8];
    __shared__ int tot[NCH_];
    __shared__ int bbase[NCH_ + 1];
    const int t = threadIdx.x;

#pragma unroll
    for (int c = 0; c < NCH_; ++c) lcnt[t * NCH_ + c] = 0;
    __syncthreads();

    for (int p = t; p < NPAIR_; p += 512) {
        int id = ids[p];
        if (id != 0) lcnt[t * NCH_ + (id / CHUNK_)] += 1;
    }
    __syncthreads();

    if (t < NCH_ * 8) {
        int bkt = t >> 3, seg = t & 7;
        int run = 0;
        for (int i = 0; i < 64; ++i) {
            int idx = (seg * 64 + i) * NCH_ + bkt;
            int tmp = lcnt[idx];
            lcnt[idx] = run;
            run += tmp;
        }
        segtot[bkt][seg] = run;
    }
    __syncthreads();
    if (t < NCH_) {
        int run = 0;
#pragma unroll
        for (int s = 0; s < 8; ++s) { int tmp = segtot[t][s]; segtot[t][s] = run; run += tmp; }
        tot[t] = run;
    }
    __syncthreads();
    if (t == 0) {
        int run = 0;
#pragma unroll
        for (int c = 0; c < NCH_; ++c) { bbase[c] = run; run += tot[c]; }
        bbase[NCH_] = run;
#pragma unroll
        for (int c = 0; c <= NCH_; ++c) chunkstart[c] = bbase[c];
    }
    __syncthreads();
    if (t < NCH_ * 8) {
        int bkt = t >> 3, seg = t & 7;
        int add = segtot[bkt][seg];
        for (int i = 0; i < 64; ++i) lcnt[(seg * 64 + i) * NCH_ + bkt] += add;
    }
    __syncthreads();

    for (int p = t; p < NPAIR_; p += 512) {
        int id = ids[p];
        if (id == 0) continue;
        int bkt = id / CHUNK_;
        int pos = bbase[bkt] + lcnt[t * NCH_ + bkt];
        lcnt[t * NCH_ + bkt] += 1;
        int2 mm;
        mm.x = id;
        mm.y = p | (tabv[p] << 16);        // p < 2^15, tab < 121 < 2^7
        smeta[pos] = mm;
    }
}

// ---------------------------------------------------------------------------
// pair body: bit-identical arithmetic to all passing rounds (trig from table)
// ---------------------------------------------------------------------------
__device__ __forceinline__ void pair_body2(const int2 m, const float2* __restrict__ sb,
                                           int lo, const float2* __restrict__ trig,
                                           float* __restrict__ pcontrib) {
    int id  = m.x;
    int dst = m.y & 0xFFFF;
    int tab = m.y >> 16;
    float2 o = trig[tab];
    float2 g = sb[id - lo];
    float wabs = sqrtf(__fadd_rn(__fmul_rn(g.x, g.x), __fmul_rn(g.y, g.y)));
    float pre = __fadd_rn(__fmul_rn(g.x, o.x), __fmul_rn(g.y, o.y));
    float pim = __fsub_rn(__fmul_rn(g.y, o.x), __fmul_rn(g.x, o.y));
    if (pre < 1e-10f && pre > -1e-10f) pre = 1e-10f;
    if (pim < 1e-10f && pim > -1e-10f) pim = 1e-10f;
    float ang = fabsf(atan2f(pim, pre));
    pcontrib[dst] = __fadd_rn(wabs, ang);
}

// ---------------------------------------------------------------------------
// Kernel B: persistent, 1 block/CU, producer/consumer wave specialization
// (R8 skeleton). Producer = waves 0-3 (256 thr): 4 named vf4 regs/chunk,
// 4-set rotation, NON-TEMPORAL W loads (keep L2 for smeta). Consumer =
// waves 4-15 (768 thr): 8-byte smeta + 121-entry LDS trig table.
// Barriers drain lgkm ONLY; vmcnt waits compiler-derived per wave-role.
// ---------------------------------------------------------------------------
__global__ __launch_bounds__(PFTH_, 1) void pf_kernel(const vf4* __restrict__ W4,
                                                      const int2* __restrict__ smeta,
                                                      const int* __restrict__ chunkstart,
                                                      float* __restrict__ pfT) {
    extern __shared__ char smem[];
    float* pcontrib = (float*)smem;                        // [NPAIR_]
    char*  sbuf     = smem + PCON_BYTES_;                  // [4][16 KB]
    __shared__ int cstart[NCH_ + 1];
    __shared__ float2 trigS[121];

    const int t = threadIdx.x;
    const int kbase = blockIdx.x * KPB_;

    if (t <= NCH_) cstart[t] = chunkstart[t];
    if (t < 121) {                                         // bit-identical to prep's formula
        int pp = t / 11 + 1, ss = t % 11 + 1;
        float pos = __fdiv_rn(__fmul_rn(PI_F, (float)pp), (float)ss);
        trigS[t] = make_float2(cosf(pos), sinf(pos));
    }

#define LOADCH(GP, R0, R1, R2, R3)                                               \
    {   int g2_ = (GP);                                                          \
        if (g2_ < GTOT_) {                                                       \
            int kk2_ = g2_ / NCH_, cc2_ = g2_ % NCH_;                            \
            int nu2_ = (cc2_ == NCH_ - 1) ? TAILU_ : UNITS_;                     \
            const vf4* s2_ = W4 + (size_t)(kbase + kk2_) * UPK_ + (size_t)cc2_ * UNITS_; \
            if (t < nu2_)            R0 = __builtin_nontemporal_load(&s2_[t]);   \
            if (PRT_ + t < nu2_)     R1 = __builtin_nontemporal_load(&s2_[PRT_ + t]); \
            if (2 * PRT_ + t < nu2_) R2 = __builtin_nontemporal_load(&s2_[2 * PRT_ + t]); \
            if (3 * PRT_ + t < nu2_) R3 = __builtin_nontemporal_load(&s2_[3 * PRT_ + t]); \
        }                                                                        \
    }

    // producer 4-set named regs; consumer smeta ping-pong
    vf4 a0, a1, a2, a3, b0, b1, b2, b3, c0, c1, c2, c3, d0, d1, d2, d3;
    int2 A0{}, A1{}, B0{}, B1{};

    // ---- prologue
    if (t < PRT_) {
        LOADCH(0, a0, a1, a2, a3)
        {   vf4* db = (vf4*)sbuf;                  // chunk 0 is full (1024 units)
            db[t] = a0; db[PRT_ + t] = a1;
            db[2 * PRT_ + t] = a2; db[3 * PRT_ + t] = a3; }
        LOADCH(1, b0, b1, b2, b3)
        LOADCH(2, c0, c1, c2, c3)
        LOADCH(3, d0, d1, d2, d3)
    } else {
        int ct = t - PRT_;
        int q0 = ct;         if (q0 > NPAIR_ - 1) q0 = NPAIR_ - 1;
        int q1 = CNT_ + ct;  if (q1 > NPAIR_ - 1) q1 = NPAIR_ - 1;
        A0 = smeta[q0]; A1 = smeta[q1];
    }
    for (int i = t; i < NPAIR_; i += PFTH_) pcontrib[i] = 0.0f;
    asm volatile("s_waitcnt vmcnt(0) lgkmcnt(0)" ::: "memory");
    __builtin_amdgcn_s_barrier();
    __builtin_amdgcn_sched_barrier(0);

#define PHASE(J, L0, L1, L2, L3, Wr0, Wr1, Wr2, Wr3, SU0, SU1, SL0, SL1)         \
    {                                                                            \
        const int p_ = g + (J);                                                  \
        __builtin_amdgcn_sched_barrier(0);                                       \
        asm volatile("s_waitcnt lgkmcnt(0)" ::: "memory");                       \
        __builtin_amdgcn_s_barrier();                                            \
        __builtin_amdgcn_sched_barrier(0);                                       \
        int ccj_ = cc + (J); int kkj_ = kk;                                      \
        if (ccj_ >= NCH_) { ccj_ -= NCH_; kkj_ += 1; }                           \
        if (t < PRT_) {                                                          \
            if (p_ + 1 < GTOT_) {                                                \
                int cw_ = ccj_ + 1; if (cw_ >= NCH_) cw_ = 0;                    \
                int nw_ = (cw_ == NCH_ - 1) ? TAILU_ : UNITS_;                   \
                vf4* db_ = (vf4*)(sbuf + (size_t)((p_ + 1) & 3) * (CHUNK_ * 8)); \
                if (t < nw_)            db_[t] = Wr0;                            \
                if (PRT_ + t < nw_)     db_[PRT_ + t] = Wr1;                     \
                if (2 * PRT_ + t < nw_) db_[2 * PRT_ + t] = Wr2;                 \
                if (3 * PRT_ + t < nw_) db_[3 * PRT_ + t] = Wr3;                 \
            }                                                                    \
            LOADCH(p_ + 4, L0, L1, L2, L3)                                       \
        } else {                                                                 \
            const int ct_ = t - PRT_;                                            \
            {   int cn_ = ccj_ + 1; if (cn_ >= NCH_) cn_ = 0;                    \
                int ns_ = cstart[cn_];                                           \
                int q0_ = ns_ + ct_;         if (q0_ > NPAIR_ - 1) q0_ = NPAIR_ - 1; \
                int q1_ = ns_ + CNT_ + ct_;  if (q1_ > NPAIR_ - 1) q1_ = NPAIR_ - 1; \
                SL0 = smeta[q0_]; SL1 = smeta[q1_]; }                            \
            {   const float2* sb_ = (const float2*)(sbuf + (size_t)(p_ & 3) * (CHUNK_ * 8)); \
                const int lo_ = ccj_ * CHUNK_;                                   \
                const int cs_ = cstart[ccj_], ce_ = cstart[ccj_ + 1];            \
                if (cs_ + ct_ < ce_)        pair_body2(SU0, sb_, lo_, trigS, pcontrib); \
                if (cs_ + CNT_ + ct_ < ce_) pair_body2(SU1, sb_, lo_, trigS, pcontrib); \
                for (int pp_ = cs_ + 2 * CNT_ + ct_; pp_ < ce_; pp_ += CNT_)     \
                    pair_body2(smeta[pp_], sb_, lo_, trigS, pcontrib); }         \
        }                                                                        \
        if (ccj_ == NCH_ - 1) {                                                  \
            __builtin_amdgcn_sched_barrier(0);                                   \
            asm volatile("s_waitcnt lgkmcnt(0)" ::: "memory");                   \
            __builtin_amdgcn_s_barrier();                                        \
            __builtin_amdgcn_sched_barrier(0);                                   \
            float* outp_ = pfT + (size_t)(kbase + kkj_) * B_;                    \
            _Pragma("unroll")                                                    \
            for (int i_ = 0; i_ < B_ / PFTH_; ++i_) {                            \
                int b_ = i_ * PFTH_ + t;                                         \
                float acc_ = 0.0f;                                               \
                _Pragma("unroll")                                                \
                for (int w_ = 0; w_ < WIN_; ++w_)                                \
                    acc_ = __fadd_rn(acc_, pcontrib[b_ * WIN_ + w_]);            \
                outp_[b_] = acc_;                                                \
            }                                                                    \
        }                                                                        \
    }

#pragma unroll 1
    for (int g = 0; g < GTOT_; g += 4) {
        const int cc = g % NCH_, kk = g / NCH_;
        PHASE(0, a0, a1, a2, a3, b0, b1, b2, b3, A0, A1, B0, B1)
        PHASE(1, b0, b1, b2, b3, c0, c1, c2, c3, B0, B1, A0, A1)
        PHASE(2, c0, c1, c2, c3, d0, d1, d2, d3, A0, A1, B0, B1)
        PHASE(3, d0, d1, d2, d3, a0, a1, a2, a3, B0, B1, A0, A1)
    }
#undef PHASE
#undef LOADCH
}

// ---------------------------------------------------------------------------
// Kernel T: transpose [K,B] -> [B,K] via 64x64 LDS tiles
// ---------------------------------------------------------------------------
__global__ __launch_bounds__(256) void transpose_kb(const float* __restrict__ pfT,
                                                    float* __restrict__ pf) {
    __shared__ float tile[64][65];
    int kb = blockIdx.x * 64;
    int bb = blockIdx.y * 64;
    int tx = threadIdx.x & 63;
    int ty = threadIdx.x >> 6;
#pragma unroll
    for (int i = 0; i < 64; i += 4)
        tile[ty + i][tx] = pfT[(size_t)(kb + ty + i) * B_ + (bb + tx)];
    __syncthreads();
#pragma unroll
    for (int i = 0; i < 64; i += 4)
        pf[(size_t)(bb + ty + i) * K_ + (kb + tx)] = tile[tx][ty + i];
}

// ---------------------------------------------------------------------------
// Kernel C: per-row exact top-64 (radix select, jax tie semantics) + logits.
// ---------------------------------------------------------------------------
__global__ __launch_bounds__(256) void topk_logits_kernel(const float* __restrict__ pf,
                                                          const float* __restrict__ w_out,
                                                          const float* __restrict__ b_out,
                                                          float* __restrict__ out) {
    const int b = blockIdx.x;
    const int t = threadIdx.x;
    __shared__ uint32_t srow[K_];
    __shared__ int hist[256];
    __shared__ int sfx[256];
    __shared__ uint32_t sh_prefix;
    __shared__ int sh_need;
    __shared__ int wave_gt[4], wave_eq[4];
    __shared__ int gt_running, eq_running;
    __shared__ int idxlist[TOPK_];
    __shared__ float partial[4][NOUT_];

    const float* rowp = pf + (size_t)b * K_;
    for (int i = t; i < K_; i += 256) srow[i] = __float_as_uint(rowp[i]);
    if (t == 0) { sh_prefix = 0u; sh_need = TOPK_; gt_running = 0; eq_running = 0; }
    __syncthreads();

    for (int pass = 0; pass < 4; ++pass) {
        int shift = 24 - 8 * pass;
        uint32_t himask = (pass == 0) ? 0u : (0xFFFFFFFFu << (shift + 8));
        hist[t] = 0;
        __syncthreads();
        uint32_t prefix = sh_prefix & himask;
        for (int i = t; i < K_; i += 256) {
            uint32_t u = srow[i];
            if ((u & himask) == prefix) atomicAdd(&hist[(u >> shift) & 255], 1);
        }
        __syncthreads();
        sfx[t] = hist[t];
        __syncthreads();
#pragma unroll
        for (int off = 1; off < 256; off <<= 1) {
            int v = (t + off < 256) ? sfx[t + off] : 0;
            __syncthreads();
            sfx[t] += v;
            __syncthreads();
        }
        int need = sh_need;
        int above = (t == 255) ? 0 : sfx[t + 1];
        if (sfx[t] >= need && above < need) {
            sh_prefix |= ((uint32_t)t << shift);
            sh_need = need - above;
        }
        __syncthreads();
    }
    const uint32_t T = sh_prefix;
    const int r = sh_need;
    const int c_gt = TOPK_ - r;

    for (int cbase = 0; cbase < K_; cbase += 256) {
        uint32_t u = srow[cbase + t];
        bool gt = (u > T);
        bool eq = (u == T);
        unsigned long long mg = __ballot(gt);
        unsigned long long me = __ballot(eq);
        int lane = t & 63, wv = t >> 6;
        if (lane == 0) { wave_gt[wv] = __popcll(mg); wave_eq[wv] = __popcll(me); }
        __syncthreads();
        int offg = gt_running, offe = eq_running;
        for (int w2 = 0; w2 < wv; ++w2) { offg += wave_gt[w2]; offe += wave_eq[w2]; }
        unsigned long long lmask = (lane == 0) ? 0ull : ((~0ull) >> (64 - lane));
        int rkg = offg + __popcll(mg & lmask);
        int rke = offe + __popcll(me & lmask);
        if (gt) idxlist[rkg] = cbase + t;
        else if (eq && rke < r) idxlist[c_gt + rke] = cbase + t;
        __syncthreads();
        if (t == 0) {
            gt_running += wave_gt[0] + wave_gt[1] + wave_gt[2] + wave_gt[3];
            eq_running += wave_eq[0] + wave_eq[1] + wave_eq[2] + wave_eq[3];
        }
        __syncthreads();
    }

    {
        int lane = t & 63, wv4 = t >> 6;
        if (lane < NOUT_) {
            const float* wrow = w_out + (size_t)lane * K_;
            float s = 0.0f;
#pragma unroll
            for (int j = 0; j < TOPK_ / 4; ++j) s += wrow[idxlist[wv4 * (TOPK_ / 4) + j]];
            partial[wv4][lane] = s;
        }
        __syncthreads();
        if (t < NOUT_) {
            float s = b_out[t] + partial[0][t] + partial[1][t] + partial[2][t] + partial[3][t];
            out[b * NOUT_ + t] = s;
        }
    }
}

// ---------------------------------------------------------------------------
extern "C" void kernel_launch(void* const* d_in, const int* in_sizes, int n_in,
                              void* d_out, int out_size, void* d_ws, size_t ws_size,
                              hipStream_t stream) {
    const int*   ids   = (const int*)d_in[0];
    const float* W     = (const float*)d_in[1];
    const float* w_out = (const float*)d_in[2];
    const float* b_out = (const float*)d_in[3];
    float* out = (float*)d_out;

    char* ws = (char*)d_ws;
    const size_t pf_bytes = (size_t)K_ * B_ * sizeof(float);   // 33.55 MB
    float* pfT   = (float*)(ws);                               // [K, B]
    float* pf    = (float*)(ws + pf_bytes);                    // [B, K]
    int*   tabv  = (int*)(ws + 2 * pf_bytes);                  // [NPAIR_] (88 KB)
    int2*  smeta = (int2*)(ws + 2 * pf_bytes + 256 * 1024);    // [NPAIR_] (180 KB)
    int* chunkstart = (int*)(ws + 2 * pf_bytes + 768 * 1024);  // [NCH_+1]

    (void)hipFuncSetAttribute((const void*)pf_kernel,
                              hipFuncAttributeMaxDynamicSharedMemorySize,
                              SMEM_BYTES_);

    prep_kernel<<<(B_ + 255) / 256, 256, 0, stream>>>(ids, tabv);
    bucket_kernel<<<1, 512, 0, stream>>>(ids, tabv, smeta, chunkstart);
    pf_kernel<<<NBLK_, PFTH_, SMEM_BYTES_, stream>>>((const vf4*)W, smeta, chunkstart, pfT);
    transpose_kb<<<dim3(K_ / 64, B_ / 64), 256, 0, stream>>>(pfT, pf);
    topk_logits_kernel<<<B_, 256, 0, stream>>>(pf, w_out, b_out, out);
}